// Round 11
// baseline (145.118 us; speedup 1.0000x reference)
//
#include <hip/hip_runtime.h>
#include <math.h>

typedef unsigned short u16;
typedef unsigned int   u32;
typedef __bf16 bf16x8 __attribute__((ext_vector_type(8)));
typedef float  f32x4  __attribute__((ext_vector_type(4)));

#define B_ROWS 16384
#define PC 16
#define EPS_SIM 1e-4f
#define LOG_MIN_F (-18.420680743952367f)
#define KL_IDX  (B_ROWS + B_ROWS * 512)   // 8404992
#define OR_IDX  (KL_IDX + 1)

// direct global->LDS async copy, 16B per lane (lds dest = uniform base + lane*16)
#define GLD16(gp, lp) __builtin_amdgcn_global_load_lds( \
    (const __attribute__((address_space(1))) void*)(gp), \
    (__attribute__((address_space(3))) void*)(lp), 16, 0, 0)

__device__ inline u16 f2bf(float f) {
    u32 u = __float_as_uint(f);
    return (u16)((u + 0x7FFFu + ((u >> 16) & 1u)) >> 16);
}
__device__ inline float bf2f(u16 h) { return __uint_as_float(((u32)h) << 16); }

// ---------------------------------------------------------------------------
// prep: ortho partials (blocks 0-7 -> opart[c], plain stores) + splits +
// pnorm + init.  NO accumulation into d_out here (replay-idempotent).
// ---------------------------------------------------------------------------
__device__ __forceinline__ void split4(const float* __restrict__ src,
                                       u16* __restrict__ hi, u16* __restrict__ lo,
                                       int i)
{
    float4 v = ((const float4*)src)[i];
    float f[4] = {v.x, v.y, v.z, v.w};
    u16 h[4], l[4];
#pragma unroll
    for (int k = 0; k < 4; ++k) {
        h[k] = f2bf(f[k]);
        l[k] = f2bf(f[k] - bf2f(h[k]));
    }
    ((ushort4*)hi)[i] = make_ushort4(h[0], h[1], h[2], h[3]);
    ((ushort4*)lo)[i] = make_ushort4(l[0], l[1], l[2], l[3]);
}

__global__ __launch_bounds__(256)
void prep_kernel(const float* __restrict__ x,   const float* __restrict__ W1,
                 const float* __restrict__ W2,  const float* __restrict__ Wd1,
                 const float* __restrict__ Wd2, const float* __restrict__ protos,
                 u16* __restrict__ x_h,  u16* __restrict__ x_l,
                 u16* __restrict__ W1h,  u16* __restrict__ W1l,
                 u16* __restrict__ W2h,  u16* __restrict__ W2l,
                 u16* __restrict__ Wd1h, u16* __restrict__ Wd1l,
                 u16* __restrict__ Wd2h, u16* __restrict__ Wd2l,
                 u16* __restrict__ ph,   u16* __restrict__ pl,
                 float* __restrict__ pnorm, float* __restrict__ opart,
                 float* __restrict__ S, float* __restrict__ Mn,
                 float* __restrict__ out)
{
    __shared__ float pk[PC][257];
    __shared__ float red[256];
    int blk = blockIdx.x, t = threadIdx.x;

    if (blk < 8) {                      // ortho: one class per block, parallel
        int c = blk;
        for (int i = t; i < PC * 256; i += 256)
            pk[i >> 8][i & 255] = protos[c * PC * 256 + i];
        __syncthreads();
        float mean = 0.f;
#pragma unroll
        for (int i = 0; i < PC; ++i) mean += pk[i][t];
        mean *= (1.f / (float)PC);
#pragma unroll
        for (int i = 0; i < PC; ++i) pk[i][t] -= mean;
        __syncthreads();
        int i = t >> 4, j = t & 15;
        float gg = 0.f;
#pragma unroll 8
        for (int l = 0; l < 256; ++l) gg = fmaf(pk[i][l], pk[j][l], gg);
        gg -= (i == j) ? 1.f : 0.f;
        red[t] = gg * gg;
        __syncthreads();
        for (int s = 128; s; s >>= 1) { if (t < s) red[t] += red[t + s]; __syncthreads(); }
        if (t == 0) opart[c] = sqrtf(red[0]);     // plain store, summed later
        return;
    }
    int b2 = blk - 8;
    if (b2 < 8192)         split4(x,   x_h,  x_l,  b2 * 256 + t);
    else if (b2 < 8448)    split4(W1,  W1h,  W1l,  (b2 - 8192) * 256 + t);
    else if (b2 < 8704)    split4(W2,  W2h,  W2l,  (b2 - 8448) * 256 + t);
    else if (b2 < 8768)    split4(Wd1, Wd1h, Wd1l, (b2 - 8704) * 256 + t);
    else if (b2 < 8896)    split4(Wd2, Wd2h, Wd2l, (b2 - 8768) * 256 + t);
    else if (b2 < 8928)    split4(protos, ph, pl,  (b2 - 8896) * 256 + t);
    else if (b2 < 8930) {
        int tt = (b2 - 8928) * 256 + t;            // [0,512)
        int row = tt >> 2, q = tt & 3;
        const float* pr = protos + (size_t)row * 256 + q * 64;
        float s = 0.f;
#pragma unroll
        for (int j = 0; j < 16; ++j) {
            float4 v = *(const float4*)(pr + j * 4);
            s = fmaf(v.x, v.x, s); s = fmaf(v.y, v.y, s);
            s = fmaf(v.z, v.z, s); s = fmaf(v.w, v.w, s);
        }
        s += __shfl_xor(s, 1, 64);
        s += __shfl_xor(s, 2, 64);
        if (q == 0) pnorm[row] = s;
    } else {
        int i = (b2 - 8930) * 256 + t;             // [0,16384)
        S[i] = 0.f; Mn[i] = 0.f;
        if (i == 0) out[KL_IDX] = 0.f;
    }
}

// ---------------------------------------------------------------------------
// Split-bf16 MFMA GEMM, BM=64 x BN=64, BK=32, 4 waves (2x2), 16KB LDS,
// __launch_bounds__(256,8) -> 8 blocks/CU: throughput-over-latency.
// Two-barrier loop: barrier -> ds_read frags -> barrier -> stage(tk+1) -> MFMA.
// MODE 0: relu -> split store
// MODE 3: tanh -> f32 store
// MODE 4: y<4 mu split store + |mu|^2 row-reduce; y>=4 logVar -> S row-reduce
// MODE 5: y<4 relu split store (dh); y in {4,5} proto-distance epilogue + kl;
//         block (x=0,y=4) also finalizes ortho from opart (stream-ordered
//         after prep, single plain store -> replay-deterministic)
// ---------------------------------------------------------------------------
template<int MODE, int KK>
__global__ __launch_bounds__(256, 8)
void gemm_mfma(const u16* __restrict__ Ah_g, const u16* __restrict__ Al_g,
               const u16* __restrict__ Bh_g, const u16* __restrict__ Bl_g,
               const u16* __restrict__ Ph,   const u16* __restrict__ Pl,
               const float* __restrict__ bias,
               u16* __restrict__ Ch, u16* __restrict__ Cl,
               float* __restrict__ Cf,
               float* __restrict__ Srow, float* __restrict__ Mnorm,
               const int* __restrict__ tcls, const float* __restrict__ pnorm,
               const float* __restrict__ Wlast, const float* __restrict__ opart,
               float* __restrict__ out, float* __restrict__ kl_out,
               int ldc)
{
    __shared__ __align__(16) u16 LAh[64][32];
    __shared__ __align__(16) u16 LAl[64][32];
    __shared__ __align__(16) u16 LBh[64][32];
    __shared__ __align__(16) u16 LBl[64][32];
    __shared__ float klacc;

    const int t = threadIdx.x, lane = t & 63, wave = t >> 6;
    const int wm = wave >> 1, wn = wave & 1;
    const int bm = blockIdx.x * 64;
    const int y  = blockIdx.y;
    const bool proto = (MODE == 5) && (y >= 4);
    const int bn  = y * 64;                       // output col base (non-proto)
    const int bnB = proto ? (y - 4) * 64 : bn;    // B row base
    const u16* Bh_p = proto ? Ph : Bh_g;
    const u16* Bl_p = proto ? Pl : Bl_g;
    const int rA = lane & 15, g = lane >> 4;
    const int srow = lane >> 2, cp = lane & 3;    // staging: 16 rows x 4 chunks

    if (t == 0) klacc = 0.f;

    f32x4 acc[2][2];
    const f32x4 z4 = {0.f, 0.f, 0.f, 0.f};
#pragma unroll
    for (int i = 0; i < 2; ++i)
#pragma unroll
        for (int j = 0; j < 2; ++j) acc[i][j] = z4;

    auto stage = [&](int kt) {   // 4 GLD16 per thread
        int row = wave * 16 + srow;
        int lc  = (cp - (row >> 1)) & 3;          // inverse swizzle on SOURCE
        size_t goffA = (size_t)(bm  + row) * KK + kt * 32 + lc * 8;
        size_t goffB = (size_t)(bnB + row) * KK + kt * 32 + lc * 8;
        GLD16(Ah_g + goffA, &LAh[wave * 16][0]);
        GLD16(Al_g + goffA, &LAl[wave * 16][0]);
        GLD16(Bh_p + goffB, &LBh[wave * 16][0]);
        GLD16(Bl_p + goffB, &LBl[wave * 16][0]);
    };

    constexpr int T = KK / 32;
    stage(0);
    for (int tk = 0; tk < T; ++tk) {
        __syncthreads();                 // vmcnt drained: tile tk in LDS

        bf16x8 aH[2], aL[2], bH[2], bL[2];
#pragma unroll
        for (int i = 0; i < 2; ++i) {
            int m = wm * 32 + i * 16 + rA;
            int c = ((g + (m >> 1)) & 3) * 8;     // swizzled READ
            aH[i] = *(const bf16x8*)&LAh[m][c];
            aL[i] = *(const bf16x8*)&LAl[m][c];
        }
#pragma unroll
        for (int j = 0; j < 2; ++j) {
            int n = wn * 32 + j * 16 + rA;
            int c = ((g + (n >> 1)) & 3) * 8;
            bH[j] = *(const bf16x8*)&LBh[n][c];
            bL[j] = *(const bf16x8*)&LBl[n][c];
        }

        __syncthreads();                 // all reads done; safe to overwrite
        if (tk + 1 < T) stage(tk + 1);   // loads fly under the 12 MFMAs

#pragma unroll
        for (int i = 0; i < 2; ++i)
#pragma unroll
            for (int j = 0; j < 2; ++j) {
                acc[i][j] = __builtin_amdgcn_mfma_f32_16x16x32_bf16(aH[i], bH[j], acc[i][j], 0, 0, 0);
                acc[i][j] = __builtin_amdgcn_mfma_f32_16x16x32_bf16(aL[i], bH[j], acc[i][j], 0, 0, 0);
                acc[i][j] = __builtin_amdgcn_mfma_f32_16x16x32_bf16(aH[i], bL[j], acc[i][j], 0, 0, 0);
            }
    }

    if (proto) {
        // d^2 = |mu|^2 + |p|^2 - 2*cross for class slab cols cls*16..+15
        const int pb = (y - 4) * 64;              // global proto base of block
        float pn[2], wl[2];
#pragma unroll
        for (int j = 0; j < 2; ++j) {
            int gp = pb + wn * 32 + j * 16 + rA;
            pn[j] = pnorm[gp];
            wl[j] = Wlast[gp];
        }
#pragma unroll
        for (int i = 0; i < 2; ++i)
#pragma unroll
            for (int r = 0; r < 4; ++r) {
                int row = bm + wm * 32 + i * 16 + g * 4 + r;
                int cls = tcls[row];
                bool owner = ((cls >> 2) == (y - 4)) && (((cls >> 1) & 1) == wn);
                int jsel = cls & 1;
                float cv = 0.f, pnv = 0.f, wlv = 0.f;
#pragma unroll
                for (int j = 0; j < 2; ++j) {
                    bool sel = (j == jsel);
                    cv  = sel ? acc[i][j][r] : cv;
                    pnv = sel ? pn[j] : pnv;
                    wlv = sel ? wl[j] : wlv;
                }
                float dd  = fmaxf(Mnorm[row] + pnv - 2.f * cv, 0.f);
                float d   = sqrtf(dd);
                float sim = __logf((d + 1.0f) / (d + EPS_SIM));
                float kl  = Srow[row] + dd * (0.5f / 256.f);
                float klw = kl * sim;
                float num = klw;
                float den = (klw > 0.0f) ? sim : 0.0f;
                float ov  = sim * wlv;
                num += __shfl_xor(num, 1, 64); den += __shfl_xor(den, 1, 64); ov += __shfl_xor(ov, 1, 64);
                num += __shfl_xor(num, 2, 64); den += __shfl_xor(den, 2, 64); ov += __shfl_xor(ov, 2, 64);
                num += __shfl_xor(num, 4, 64); den += __shfl_xor(den, 4, 64); ov += __shfl_xor(ov, 4, 64);
                num += __shfl_xor(num, 8, 64); den += __shfl_xor(den, 8, 64); ov += __shfl_xor(ov, 8, 64);
                if (owner && rA == 0) {
                    out[row] = ov;
                    atomicAdd(&klacc, num / den);   // LDS atomic
                }
            }
        __syncthreads();
        if (t == 0 && klacc != 0.f) atomicAdd(kl_out, klacc * (1.f / (float)B_ROWS));
        // ortho finalize: ONE thread on the whole grid, plain store
        if (blockIdx.x == 0 && y == 4 && t == 0) {
            float o = 0.f;
#pragma unroll
            for (int c = 0; c < 8; ++c) o += opart[c];
            out[OR_IDX] = o * (1.f / 8.f);
        }
        return;
    }

    float bv[2];
#pragma unroll
    for (int j = 0; j < 2; ++j) bv[j] = bias[bn + wn * 32 + j * 16 + rA];

    if (MODE == 4 && y >= 4) {
        // logVar columns: S[row] += partial mean(0.5 e^lv - 0.5 lv - 0.5)
#pragma unroll
        for (int i = 0; i < 2; ++i)
#pragma unroll
            for (int r = 0; r < 4; ++r) {
                int row = bm + wm * 32 + i * 16 + g * 4 + r;
                float s = 0.f;
#pragma unroll
                for (int j = 0; j < 2; ++j) {
                    float lv = acc[i][j][r] + bv[j];
                    lv = fminf(fmaxf(lv, LOG_MIN_F), -LOG_MIN_F);
                    s += 0.5f * __expf(lv) - 0.5f * lv - 0.5f;
                }
                s += __shfl_xor(s, 1, 64); s += __shfl_xor(s, 2, 64);
                s += __shfl_xor(s, 4, 64); s += __shfl_xor(s, 8, 64);
                if (rA == 0) atomicAdd(&Srow[row], s * (1.f / 256.f));
            }
        return;
    }

#pragma unroll
    for (int i = 0; i < 2; ++i)
#pragma unroll
        for (int r = 0; r < 4; ++r) {
            size_t row = bm + wm * 32 + i * 16 + g * 4 + r;
            float sq = 0.f;
#pragma unroll
            for (int j = 0; j < 2; ++j) {
                int col = bn + wn * 32 + j * 16 + rA;
                float v = acc[i][j][r] + bv[j];
                if (MODE == 0 || MODE == 5) v = fmaxf(v, 0.f);
                if (MODE == 3) {
                    float e = __expf(2.f * v);
                    Cf[row * ldc + col] = 1.f - 2.f / (e + 1.f);
                } else {
                    u16 hh = f2bf(v);
                    u16 ll = f2bf(v - bf2f(hh));
                    Ch[row * ldc + col] = hh;
                    Cl[row * ldc + col] = ll;
                    if (MODE == 4) sq = fmaf(v, v, sq);
                }
            }
            if (MODE == 4) {   // |mu|^2 partial for this wave's 32 cols
                sq += __shfl_xor(sq, 1, 64); sq += __shfl_xor(sq, 2, 64);
                sq += __shfl_xor(sq, 4, 64); sq += __shfl_xor(sq, 8, 64);
                if (rA == 0) atomicAdd(&Mnorm[row], sq);
            }
        }
}

// ---------------------------------------------------------------------------
extern "C" void kernel_launch(void* const* d_in, const int* in_sizes, int n_in,
                              void* d_out, int out_size, void* d_ws, size_t ws_size,
                              hipStream_t stream)
{
    const float* x      = (const float*)d_in[0];
    const int*   tcls   = (const int*)  d_in[1];
    const float* protos = (const float*)d_in[2];
    const float* W1     = (const float*)d_in[3];
    const float* b1     = (const float*)d_in[4];
    const float* W2     = (const float*)d_in[5];
    const float* b2     = (const float*)d_in[6];
    const float* Wd1    = (const float*)d_in[7];
    const float* bd1    = (const float*)d_in[8];
    const float* Wd2    = (const float*)d_in[9];
    const float* bd2    = (const float*)d_in[10];
    const float* Wlast  = (const float*)d_in[11];

    float* out     = (float*)d_out;
    float* decoded = out + B_ROWS;

    // h (split bf16) lives in d_out's decoded region (33.55MB), overwritten by G4
    u16* h_h = (u16*)decoded;
    u16* h_l = h_h + 8388608;

    // workspace overlays: x region (32MB) reused for mu + dh after G1
    u16* wsu  = (u16*)d_ws;
    u16* x_h  = wsu;
    u16* x_l  = wsu + 8388608;
    u16* mu_h = wsu;
    u16* mu_l = wsu + 4194304;
    u16* dh_h = wsu + 8388608;
    u16* dh_l = wsu + 12582912;

    float* S     = (float*)((char*)d_ws + 33554432);
    float* klrow = S + 16384;                      // layout spacer
    u16* w = (u16*)(klrow + 16384);
    u16 *W1h = w, *W1l = w + 262144, *W2h = w + 524288, *W2l = w + 786432;
    u16 *Wd1h = w + 1048576, *Wd1l = w + 1114112, *Wd2h = w + 1179648, *Wd2l = w + 1310720;
    u16 *ph = w + 1441792, *pl = ph + 32768;       // protos split (128x256)
    float* munorm = (float*)(pl + 32768);          // 16384 f32
    float* pnorm  = munorm + 16384;                // 128 f32
    float* opart  = pnorm + 128;                   // 8 f32 (ortho partials)

    // prep: ortho partials + splits + pnorm + init
    hipLaunchKernelGGL(prep_kernel, dim3(9002), dim3(256), 0, stream,
                       x, W1, W2, Wd1, Wd2, protos,
                       x_h, x_l, W1h, W1l, W2h, W2l, Wd1h, Wd1l, Wd2h, Wd2l,
                       ph, pl, pnorm, opart, S, munorm, out);

    // G1: h = relu(x @ W1^T + b1) -> split bf16
    hipLaunchKernelGGL((gemm_mfma<0, 512>), dim3(256, 8), dim3(256), 0, stream,
                       x_h, x_l, W1h, W1l, (u16*)nullptr, (u16*)nullptr, b1,
                       h_h, h_l, (float*)nullptr, (float*)nullptr, (float*)nullptr,
                       (int*)nullptr, (float*)nullptr, (float*)nullptr, (float*)nullptr,
                       (float*)nullptr, (float*)nullptr, 512);
    // G2: conv = h @ W2^T + b2 -> mu split + munorm (y<4); S row-sums (y>=4)
    hipLaunchKernelGGL((gemm_mfma<4, 512>), dim3(256, 8), dim3(256), 0, stream,
                       h_h, h_l, W2h, W2l, (u16*)nullptr, (u16*)nullptr, b2,
                       mu_h, mu_l, (float*)nullptr, S, munorm,
                       (int*)nullptr, (float*)nullptr, (float*)nullptr, (float*)nullptr,
                       (float*)nullptr, (float*)nullptr, 256);
    // G3': y<4: dh = relu(mu @ Wd1^T + bd1); y in {4,5}: proto dist + sim/kl/out
    //      + ortho finalize (block x=0,y=4)
    hipLaunchKernelGGL((gemm_mfma<5, 256>), dim3(256, 6), dim3(256), 0, stream,
                       mu_h, mu_l, Wd1h, Wd1l, ph, pl, bd1,
                       dh_h, dh_l, (float*)nullptr, S, munorm,
                       tcls, pnorm, Wlast, opart, out, out + KL_IDX, 256);
    // G4: decoded = tanh(dh @ Wd2^T + bd2) -> f32 (overwrites h region)
    hipLaunchKernelGGL((gemm_mfma<3, 256>), dim3(256, 8), dim3(256), 0, stream,
                       dh_h, dh_l, Wd2h, Wd2l, (u16*)nullptr, (u16*)nullptr, bd2,
                       (u16*)nullptr, (u16*)nullptr, decoded, (float*)nullptr, (float*)nullptr,
                       (int*)nullptr, (float*)nullptr, (float*)nullptr, (float*)nullptr,
                       (float*)nullptr, (float*)nullptr, 512);
}

// Round 12
// 81.470 us; speedup vs baseline: 1.7813x; 1.7813x over previous
//
#include <hip/hip_runtime.h>
#include <math.h>

typedef unsigned short u16;
typedef unsigned int   u32;
typedef _Float16 f16;
typedef f16   f16x4 __attribute__((ext_vector_type(4)));
typedef f16   f16x8 __attribute__((ext_vector_type(8)));
typedef float f32x4 __attribute__((ext_vector_type(4)));

#define B_ROWS 16384
#define PC 16
#define EPS_SIM 1e-4f
#define LOG_MIN_F (-18.420680743952367f)
#define KL_IDX  (B_ROWS + B_ROWS * 512)   // 8404992
#define OR_IDX  (KL_IDX + 1)

// direct global->LDS async copy, 16B per lane (lds dest = uniform base + lane*16)
#define GLD16(gp, lp) __builtin_amdgcn_global_load_lds( \
    (const __attribute__((address_space(1))) void*)(gp), \
    (__attribute__((address_space(3))) void*)(lp), 16, 0, 0)

// ---------------------------------------------------------------------------
// prep: ortho partials (blocks 0-7) + f32->f16 conversions + pnorm + init
// ---------------------------------------------------------------------------
__device__ __forceinline__ void conv4(const float* __restrict__ src,
                                      f16* __restrict__ dst, int i)
{
    float4 v = ((const float4*)src)[i];
    f16x4 o = { (f16)v.x, (f16)v.y, (f16)v.z, (f16)v.w };
    ((f16x4*)dst)[i] = o;
}

__global__ __launch_bounds__(256)
void prep_kernel(const float* __restrict__ x,   const float* __restrict__ W1,
                 const float* __restrict__ W2,  const float* __restrict__ Wd1,
                 const float* __restrict__ Wd2, const float* __restrict__ protos,
                 f16* __restrict__ x_h,  f16* __restrict__ W1h,
                 f16* __restrict__ W2h,  f16* __restrict__ Wd1h,
                 f16* __restrict__ Wd2h, f16* __restrict__ ph,
                 float* __restrict__ pnorm, float* __restrict__ opart,
                 float* __restrict__ S, float* __restrict__ Mn,
                 float* __restrict__ out)
{
    __shared__ float pk[PC][257];
    __shared__ float red[256];
    int blk = blockIdx.x, t = threadIdx.x;

    if (blk < 8) {                      // ortho: one class per block, parallel
        int c = blk;
        for (int i = t; i < PC * 256; i += 256)
            pk[i >> 8][i & 255] = protos[c * PC * 256 + i];
        __syncthreads();
        float mean = 0.f;
#pragma unroll
        for (int i = 0; i < PC; ++i) mean += pk[i][t];
        mean *= (1.f / (float)PC);
#pragma unroll
        for (int i = 0; i < PC; ++i) pk[i][t] -= mean;
        __syncthreads();
        int i = t >> 4, j = t & 15;
        float gg = 0.f;
#pragma unroll 8
        for (int l = 0; l < 256; ++l) gg = fmaf(pk[i][l], pk[j][l], gg);
        gg -= (i == j) ? 1.f : 0.f;
        red[t] = gg * gg;
        __syncthreads();
        for (int s = 128; s; s >>= 1) { if (t < s) red[t] += red[t + s]; __syncthreads(); }
        if (t == 0) opart[c] = sqrtf(red[0]);     // plain store, summed later
        return;
    }
    int b2 = blk - 8;
    if (b2 < 8192)         conv4(x,   x_h,  b2 * 256 + t);
    else if (b2 < 8448)    conv4(W1,  W1h,  (b2 - 8192) * 256 + t);
    else if (b2 < 8704)    conv4(W2,  W2h,  (b2 - 8448) * 256 + t);
    else if (b2 < 8768)    conv4(Wd1, Wd1h, (b2 - 8704) * 256 + t);
    else if (b2 < 8896)    conv4(Wd2, Wd2h, (b2 - 8768) * 256 + t);
    else if (b2 < 8928)    conv4(protos, ph, (b2 - 8896) * 256 + t);
    else if (b2 < 8930) {
        // pnorm from f16-ROUNDED protos (consistent with MFMA cross term)
        int tt = (b2 - 8928) * 256 + t;            // [0,512)
        int row = tt >> 2, q = tt & 3;
        const float* pr = protos + (size_t)row * 256 + q * 64;
        float s = 0.f;
#pragma unroll
        for (int j = 0; j < 16; ++j) {
            float4 v = *(const float4*)(pr + j * 4);
            float r0 = (float)(f16)v.x, r1 = (float)(f16)v.y;
            float r2 = (float)(f16)v.z, r3 = (float)(f16)v.w;
            s = fmaf(r0, r0, s); s = fmaf(r1, r1, s);
            s = fmaf(r2, r2, s); s = fmaf(r3, r3, s);
        }
        s += __shfl_xor(s, 1, 64);
        s += __shfl_xor(s, 2, 64);
        if (q == 0) pnorm[row] = s;
    } else {
        int i = (b2 - 8930) * 256 + t;             // [0,16384)
        S[i] = 0.f; Mn[i] = 0.f;
        if (i == 0) out[KL_IDX] = 0.f;
    }
}

// ---------------------------------------------------------------------------
// Pure-f16 MFMA GEMM, BM=64 x BN=128, BK=32, 4 waves (2x2), 12KB LDS,
// two-barrier loop: barrier -> ds_read frags -> barrier -> stage(tk+1) -> MFMA.
// MODE 0: relu -> f16 store
// MODE 3: tanh -> f32 store
// MODE 4: y<2 mu f16 store + |mu_h|^2 row-reduce; y>=2 logVar -> S row-reduce
// MODE 5: y<2 relu f16 store (dh); y==2 proto-distance epilogue + kl reduce
//         + ortho finalize (block x=0)
// ---------------------------------------------------------------------------
template<int MODE, int KK>
__global__ __launch_bounds__(256, 5)
void gemm_mfma(const f16* __restrict__ A, const f16* __restrict__ B,
               const f16* __restrict__ P, const float* __restrict__ bias,
               f16* __restrict__ C16, float* __restrict__ Cf,
               float* __restrict__ Srow, float* __restrict__ Mnorm,
               const int* __restrict__ tcls, const float* __restrict__ pnorm,
               const float* __restrict__ Wlast, const float* __restrict__ opart,
               float* __restrict__ out, float* __restrict__ kl_out,
               int ldc)
{
    __shared__ __align__(16) f16 LA[64][32];
    __shared__ __align__(16) f16 LB[128][32];
    __shared__ float klacc;

    const int t = threadIdx.x, lane = t & 63, wave = t >> 6;
    const int wm = wave >> 1, wn = wave & 1;
    const int bm = blockIdx.x * 64;
    const int y  = blockIdx.y;
    const bool proto = (MODE == 5) && (y == 2);
    const int bn  = y * 128;                      // output col base (non-proto)
    const int bnB = proto ? 0 : bn;               // B row base
    const f16* Bp = proto ? P : B;
    const int rA = lane & 15, g = lane >> 4;
    const int srow = lane >> 2, cp = lane & 3;    // staging: 16 rows x 4 chunks

    if (t == 0) klacc = 0.f;

    f32x4 acc[2][4];
    const f32x4 z4 = {0.f, 0.f, 0.f, 0.f};
#pragma unroll
    for (int i = 0; i < 2; ++i)
#pragma unroll
        for (int j = 0; j < 4; ++j) acc[i][j] = z4;

    auto stage = [&](int kt) {   // 3 GLD16 per thread
        {
            int row = wave * 16 + srow;
            int lc  = (cp - (row >> 1)) & 3;      // inverse swizzle on SOURCE
            GLD16(A + (size_t)(bm + row) * KK + kt * 32 + lc * 8, &LA[wave * 16][0]);
        }
#pragma unroll
        for (int s = 0; s < 2; ++s) {
            int row = wave * 32 + s * 16 + srow;
            int lc  = (cp - (row >> 1)) & 3;
            GLD16(Bp + (size_t)(bnB + row) * KK + kt * 32 + lc * 8,
                  &LB[wave * 32 + s * 16][0]);
        }
    };

    constexpr int T = KK / 32;
    stage(0);
    for (int tk = 0; tk < T; ++tk) {
        __syncthreads();                 // vmcnt drained: tile tk in LDS

        f16x8 a[2], b[4];
#pragma unroll
        for (int i = 0; i < 2; ++i) {
            int m = wm * 32 + i * 16 + rA;
            int c = ((g + (m >> 1)) & 3) * 8;     // swizzled READ
            a[i] = *(const f16x8*)&LA[m][c];
        }
#pragma unroll
        for (int j = 0; j < 4; ++j) {
            int n = wn * 64 + j * 16 + rA;
            int c = ((g + (n >> 1)) & 3) * 8;
            b[j] = *(const f16x8*)&LB[n][c];
        }

        __syncthreads();                 // all reads done; safe to overwrite
        if (tk + 1 < T) stage(tk + 1);   // loads fly under the 8 MFMAs

#pragma unroll
        for (int i = 0; i < 2; ++i)
#pragma unroll
            for (int j = 0; j < 4; ++j)
                acc[i][j] = __builtin_amdgcn_mfma_f32_16x16x32_f16(a[i], b[j], acc[i][j], 0, 0, 0);
    }

    if (proto) {
        // d^2 = |mu_h|^2 + |p_h|^2 - 2*cross for class slab cols cls*16..+15
        float pn[4], wl[4];
#pragma unroll
        for (int j = 0; j < 4; ++j) {
            int col = wn * 64 + j * 16 + rA;
            pn[j] = pnorm[col];
            wl[j] = Wlast[col];
        }
#pragma unroll
        for (int i = 0; i < 2; ++i)
#pragma unroll
            for (int r = 0; r < 4; ++r) {
                int row = bm + wm * 32 + i * 16 + g * 4 + r;
                int cls = tcls[row];
                int jsel = cls & 3;
                bool owner = ((cls >> 2) == wn);
                float cv = 0.f, pnv = 0.f, wlv = 0.f;
#pragma unroll
                for (int j = 0; j < 4; ++j) {
                    bool sel = (j == jsel);
                    cv  = sel ? acc[i][j][r] : cv;
                    pnv = sel ? pn[j] : pnv;
                    wlv = sel ? wl[j] : wlv;
                }
                float dd  = fmaxf(Mnorm[row] + pnv - 2.f * cv, 0.f);
                float d   = sqrtf(dd);
                float sim = __logf((d + 1.0f) / (d + EPS_SIM));
                float kl  = Srow[row] + dd * (0.5f / 256.f);
                float klw = kl * sim;
                float num = klw;
                float den = (klw > 0.0f) ? sim : 0.0f;
                float ov  = sim * wlv;
                num += __shfl_xor(num, 1, 64); den += __shfl_xor(den, 1, 64); ov += __shfl_xor(ov, 1, 64);
                num += __shfl_xor(num, 2, 64); den += __shfl_xor(den, 2, 64); ov += __shfl_xor(ov, 2, 64);
                num += __shfl_xor(num, 4, 64); den += __shfl_xor(den, 4, 64); ov += __shfl_xor(ov, 4, 64);
                num += __shfl_xor(num, 8, 64); den += __shfl_xor(den, 8, 64); ov += __shfl_xor(ov, 8, 64);
                if (owner && rA == 0) {
                    out[row] = ov;
                    atomicAdd(&klacc, num / den);   // LDS atomic
                }
            }
        __syncthreads();
        if (t == 0) {
            atomicAdd(kl_out, klacc * (1.f / (float)B_ROWS));
            if (blockIdx.x == 0) {       // ortho finalize: one thread, plain store
                float o = 0.f;
#pragma unroll
                for (int c = 0; c < 8; ++c) o += opart[c];
                out[OR_IDX] = o * (1.f / 8.f);
            }
        }
        return;
    }

    float bv[4];
#pragma unroll
    for (int j = 0; j < 4; ++j) bv[j] = bias[bn + wn * 64 + j * 16 + rA];

    if (MODE == 4 && y >= 2) {
        // logVar columns: S[row] += partial mean(0.5 e^lv - 0.5 lv - 0.5)
#pragma unroll
        for (int i = 0; i < 2; ++i)
#pragma unroll
            for (int r = 0; r < 4; ++r) {
                int row = bm + wm * 32 + i * 16 + g * 4 + r;
                float s = 0.f;
#pragma unroll
                for (int j = 0; j < 4; ++j) {
                    float lv = acc[i][j][r] + bv[j];
                    lv = fminf(fmaxf(lv, LOG_MIN_F), -LOG_MIN_F);
                    s += 0.5f * __expf(lv) - 0.5f * lv - 0.5f;
                }
                s += __shfl_xor(s, 1, 64); s += __shfl_xor(s, 2, 64);
                s += __shfl_xor(s, 4, 64); s += __shfl_xor(s, 8, 64);
                if (rA == 0) atomicAdd(&Srow[row], s * (1.f / 256.f));
            }
        return;
    }

#pragma unroll
    for (int i = 0; i < 2; ++i)
#pragma unroll
        for (int r = 0; r < 4; ++r) {
            size_t row = bm + wm * 32 + i * 16 + g * 4 + r;
            float sq = 0.f;
#pragma unroll
            for (int j = 0; j < 4; ++j) {
                int col = bn + wn * 64 + j * 16 + rA;
                float v = acc[i][j][r] + bv[j];
                if (MODE == 0 || MODE == 5) v = fmaxf(v, 0.f);
                if (MODE == 3) {
                    float e = __expf(2.f * v);
                    Cf[row * ldc + col] = 1.f - 2.f / (e + 1.f);
                } else {
                    f16 hv = (f16)v;
                    C16[row * ldc + col] = hv;
                    if (MODE == 4) {       // |mu_h|^2 from the ROUNDED value
                        float vr = (float)hv;
                        sq = fmaf(vr, vr, sq);
                    }
                }
            }
            if (MODE == 4) {   // |mu|^2 partial for this wave's 64 cols
                sq += __shfl_xor(sq, 1, 64); sq += __shfl_xor(sq, 2, 64);
                sq += __shfl_xor(sq, 4, 64); sq += __shfl_xor(sq, 8, 64);
                if (rA == 0) atomicAdd(&Mnorm[row], sq);
            }
        }
}

// ---------------------------------------------------------------------------
extern "C" void kernel_launch(void* const* d_in, const int* in_sizes, int n_in,
                              void* d_out, int out_size, void* d_ws, size_t ws_size,
                              hipStream_t stream)
{
    const float* x      = (const float*)d_in[0];
    const int*   tcls   = (const int*)  d_in[1];
    const float* protos = (const float*)d_in[2];
    const float* W1     = (const float*)d_in[3];
    const float* b1     = (const float*)d_in[4];
    const float* W2     = (const float*)d_in[5];
    const float* b2     = (const float*)d_in[6];
    const float* Wd1    = (const float*)d_in[7];
    const float* bd1    = (const float*)d_in[8];
    const float* Wd2    = (const float*)d_in[9];
    const float* bd2    = (const float*)d_in[10];
    const float* Wlast  = (const float*)d_in[11];

    float* out     = (float*)d_out;
    float* decoded = out + B_ROWS;

    // h (f16, 16MB) lives in d_out's decoded region (33.5MB), overwritten by G4
    f16* h_h = (f16*)decoded;

    // workspace: x_h 16MB | mu_h 8MB | dh_h 8MB | S ... | weights ...
    f16* wsf  = (f16*)d_ws;
    f16* x_h  = wsf;                         // 8388608 f16
    f16* mu_h = wsf + 8388608;               // 4194304 f16
    f16* dh_h = wsf + 12582912;              // 4194304 f16

    float* S = (float*)((char*)d_ws + 33554432);
    f16* w = (f16*)(S + 32768);
    f16 *W1h = w, *W2h = w + 262144, *Wd1h = w + 524288, *Wd2h = w + 589824;
    f16 *ph  = w + 720896;                   // protos f16 (128x256)
    float* munorm = (float*)(w + 753664);    // 16384 f32
    float* pnorm  = munorm + 16384;          // 128 f32
    float* opart  = pnorm + 128;             // 8 f32

    // prep: ortho partials + conversions + pnorm + init
    hipLaunchKernelGGL(prep_kernel, dim3(9002), dim3(256), 0, stream,
                       x, W1, W2, Wd1, Wd2, protos,
                       x_h, W1h, W2h, Wd1h, Wd2h, ph,
                       pnorm, opart, S, munorm, out);

    // G1: h = relu(x @ W1^T + b1) -> f16
    hipLaunchKernelGGL((gemm_mfma<0, 512>), dim3(256, 4), dim3(256), 0, stream,
                       x_h, W1h, (f16*)nullptr, b1,
                       h_h, (float*)nullptr, (float*)nullptr, (float*)nullptr,
                       (int*)nullptr, (float*)nullptr, (float*)nullptr, (float*)nullptr,
                       (float*)nullptr, (float*)nullptr, 512);
    // G2: conv = h @ W2^T + b2 -> mu f16 + |mu|^2 (y<2); S row-sums (y>=2)
    hipLaunchKernelGGL((gemm_mfma<4, 512>), dim3(256, 4), dim3(256), 0, stream,
                       h_h, W2h, (f16*)nullptr, b2,
                       mu_h, (float*)nullptr, S, munorm,
                       (int*)nullptr, (float*)nullptr, (float*)nullptr, (float*)nullptr,
                       (float*)nullptr, (float*)nullptr, 256);
    // G3': y<2: dh = relu(mu @ Wd1^T + bd1); y==2: proto dist + sim/kl/out + ortho fin
    hipLaunchKernelGGL((gemm_mfma<5, 256>), dim3(256, 3), dim3(256), 0, stream,
                       mu_h, Wd1h, ph, bd1,
                       dh_h, (float*)nullptr, S, munorm,
                       tcls, pnorm, Wlast, opart,
                       out, out + KL_IDX, 256);
    // G4: decoded = tanh(dh @ Wd2^T + bd2) -> f32 (overwrites h region)
    hipLaunchKernelGGL((gemm_mfma<3, 256>), dim3(256, 4), dim3(256), 0, stream,
                       dh_h, Wd2h, (f16*)nullptr, bd2,
                       (f16*)nullptr, decoded, (float*)nullptr, (float*)nullptr,
                       (int*)nullptr, (float*)nullptr, (float*)nullptr, (float*)nullptr,
                       (float*)nullptr, (float*)nullptr, 512);
}

// Round 13
// 81.307 us; speedup vs baseline: 1.7848x; 1.0020x over previous
//
#include <hip/hip_runtime.h>
#include <math.h>

typedef unsigned short u16;
typedef unsigned int   u32;
typedef _Float16 f16;
typedef f16   f16x4 __attribute__((ext_vector_type(4)));
typedef f16   f16x8 __attribute__((ext_vector_type(8)));
typedef float f32x4 __attribute__((ext_vector_type(4)));

#define B_ROWS 16384
#define PC 16
#define EPS_SIM 1e-4f
#define LOG_MIN_F (-18.420680743952367f)
#define KL_IDX  (B_ROWS + B_ROWS * 512)   // 8404992
#define OR_IDX  (KL_IDX + 1)

// direct global->LDS async copy, 16B per lane (lds dest = uniform base + lane*16)
#define GLD16(gp, lp) __builtin_amdgcn_global_load_lds( \
    (const __attribute__((address_space(1))) void*)(gp), \
    (__attribute__((address_space(3))) void*)(lp), 16, 0, 0)

// ---------------------------------------------------------------------------
// prep: ortho partials (blocks 0-7) + f32->f16 conversions + pnorm + init
// ---------------------------------------------------------------------------
__device__ __forceinline__ void conv4(const float* __restrict__ src,
                                      f16* __restrict__ dst, int i)
{
    float4 v = ((const float4*)src)[i];
    f16x4 o = { (f16)v.x, (f16)v.y, (f16)v.z, (f16)v.w };
    ((f16x4*)dst)[i] = o;
}

__global__ __launch_bounds__(256)
void prep_kernel(const float* __restrict__ x,   const float* __restrict__ W1,
                 const float* __restrict__ W2,  const float* __restrict__ Wd1,
                 const float* __restrict__ Wd2, const float* __restrict__ protos,
                 f16* __restrict__ x_h,  f16* __restrict__ W1h,
                 f16* __restrict__ W2h,  f16* __restrict__ Wd1h,
                 f16* __restrict__ Wd2h, f16* __restrict__ ph,
                 float* __restrict__ pnorm, float* __restrict__ opart,
                 float* __restrict__ S, float* __restrict__ Mn,
                 float* __restrict__ out)
{
    __shared__ float pk[PC][257];
    __shared__ float red[256];
    int blk = blockIdx.x, t = threadIdx.x;

    if (blk < 8) {                      // ortho: one class per block, parallel
        int c = blk;
        for (int i = t; i < PC * 256; i += 256)
            pk[i >> 8][i & 255] = protos[c * PC * 256 + i];
        __syncthreads();
        float mean = 0.f;
#pragma unroll
        for (int i = 0; i < PC; ++i) mean += pk[i][t];
        mean *= (1.f / (float)PC);
#pragma unroll
        for (int i = 0; i < PC; ++i) pk[i][t] -= mean;
        __syncthreads();
        int i = t >> 4, j = t & 15;
        float gg = 0.f;
#pragma unroll 8
        for (int l = 0; l < 256; ++l) gg = fmaf(pk[i][l], pk[j][l], gg);
        gg -= (i == j) ? 1.f : 0.f;
        red[t] = gg * gg;
        __syncthreads();
        for (int s = 128; s; s >>= 1) { if (t < s) red[t] += red[t + s]; __syncthreads(); }
        if (t == 0) opart[c] = sqrtf(red[0]);     // plain store, summed later
        return;
    }
    int b2 = blk - 8;
    if (b2 < 8192)         conv4(x,   x_h,  b2 * 256 + t);
    else if (b2 < 8448)    conv4(W1,  W1h,  (b2 - 8192) * 256 + t);
    else if (b2 < 8704)    conv4(W2,  W2h,  (b2 - 8448) * 256 + t);
    else if (b2 < 8768)    conv4(Wd1, Wd1h, (b2 - 8704) * 256 + t);
    else if (b2 < 8896)    conv4(Wd2, Wd2h, (b2 - 8768) * 256 + t);
    else if (b2 < 8928)    conv4(protos, ph, (b2 - 8896) * 256 + t);
    else if (b2 < 8930) {
        // pnorm from f16-ROUNDED protos (consistent with MFMA cross term)
        int tt = (b2 - 8928) * 256 + t;            // [0,512)
        int row = tt >> 2, q = tt & 3;
        const float* pr = protos + (size_t)row * 256 + q * 64;
        float s = 0.f;
#pragma unroll
        for (int j = 0; j < 16; ++j) {
            float4 v = *(const float4*)(pr + j * 4);
            float r0 = (float)(f16)v.x, r1 = (float)(f16)v.y;
            float r2 = (float)(f16)v.z, r3 = (float)(f16)v.w;
            s = fmaf(r0, r0, s); s = fmaf(r1, r1, s);
            s = fmaf(r2, r2, s); s = fmaf(r3, r3, s);
        }
        s += __shfl_xor(s, 1, 64);
        s += __shfl_xor(s, 2, 64);
        if (q == 0) pnorm[row] = s;
    } else {
        int i = (b2 - 8930) * 256 + t;             // [0,16384)
        S[i] = 0.f; Mn[i] = 0.f;
        if (i == 0) out[KL_IDX] = 0.f;
    }
}

// ---------------------------------------------------------------------------
// Pure-f16 MFMA GEMM, BM=128 x BN=128, BK=32, 4 waves (2x2, 64x64 each),
// 16KB LDS, two-barrier loop.  64x64 wave tile: 16 MFMAs from 8 ds_reads
// (0.5 reads/MFMA, half of the previous 32x64 tile's LDS traffic per FLOP).
// MODE 0: relu -> f16 store
// MODE 3: tanh -> f32 store
// MODE 4: y<2 mu f16 store + |mu_h|^2 row-reduce; y>=2 logVar -> S row-reduce
// MODE 5: y<2 relu f16 store (dh); y==2 proto-distance epilogue + kl reduce
//         + ortho finalize (block x=0)
// ---------------------------------------------------------------------------
template<int MODE, int KK>
__global__ __launch_bounds__(256, 2)
void gemm_mfma(const f16* __restrict__ A, const f16* __restrict__ B,
               const f16* __restrict__ P, const float* __restrict__ bias,
               f16* __restrict__ C16, float* __restrict__ Cf,
               float* __restrict__ Srow, float* __restrict__ Mnorm,
               const int* __restrict__ tcls, const float* __restrict__ pnorm,
               const float* __restrict__ Wlast, const float* __restrict__ opart,
               float* __restrict__ out, float* __restrict__ kl_out,
               int ldc)
{
    __shared__ __align__(16) f16 LA[128][32];
    __shared__ __align__(16) f16 LB[128][32];
    __shared__ float klacc;

    const int t = threadIdx.x, lane = t & 63, wave = t >> 6;
    const int wm = wave >> 1, wn = wave & 1;
    const int bm = blockIdx.x * 128;
    const int y  = blockIdx.y;
    const bool proto = (MODE == 5) && (y == 2);
    const int bn  = y * 128;                      // output col base (non-proto)
    const int bnB = proto ? 0 : bn;               // B row base
    const f16* Bp = proto ? P : B;
    const int rA = lane & 15, g = lane >> 4;
    const int srow = lane >> 2, cp = lane & 3;    // staging: 16 rows x 4 chunks

    if (t == 0) klacc = 0.f;

    f32x4 acc[4][4];
    const f32x4 z4 = {0.f, 0.f, 0.f, 0.f};
#pragma unroll
    for (int i = 0; i < 4; ++i)
#pragma unroll
        for (int j = 0; j < 4; ++j) acc[i][j] = z4;

    auto stage = [&](int kt) {   // 4 GLD16 per thread (2 A-slabs + 2 B-slabs)
#pragma unroll
        for (int s = 0; s < 2; ++s) {
            int row = wave * 32 + s * 16 + srow;
            int lc  = (cp - (row >> 1)) & 3;      // inverse swizzle on SOURCE
            GLD16(A  + (size_t)(bm  + row) * KK + kt * 32 + lc * 8,
                  &LA[wave * 32 + s * 16][0]);
            GLD16(Bp + (size_t)(bnB + row) * KK + kt * 32 + lc * 8,
                  &LB[wave * 32 + s * 16][0]);
        }
    };

    constexpr int T = KK / 32;
    stage(0);
    for (int tk = 0; tk < T; ++tk) {
        __syncthreads();                 // vmcnt drained: tile tk in LDS

        f16x8 a[4], b[4];
#pragma unroll
        for (int i = 0; i < 4; ++i) {
            int m = wm * 64 + i * 16 + rA;
            int c = ((g + (m >> 1)) & 3) * 8;     // swizzled READ
            a[i] = *(const f16x8*)&LA[m][c];
            int n = wn * 64 + i * 16 + rA;
            int cn = ((g + (n >> 1)) & 3) * 8;
            b[i] = *(const f16x8*)&LB[n][cn];
        }

        __syncthreads();                 // all reads done; safe to overwrite
        if (tk + 1 < T) stage(tk + 1);   // loads fly under the 16 MFMAs

#pragma unroll
        for (int i = 0; i < 4; ++i)
#pragma unroll
            for (int j = 0; j < 4; ++j)
                acc[i][j] = __builtin_amdgcn_mfma_f32_16x16x32_f16(a[i], b[j], acc[i][j], 0, 0, 0);
    }

    if (proto) {
        // d^2 = |mu_h|^2 + |p_h|^2 - 2*cross for class slab cols cls*16..+15
        float pn[4], wl[4];
#pragma unroll
        for (int j = 0; j < 4; ++j) {
            int col = wn * 64 + j * 16 + rA;
            pn[j] = pnorm[col];
            wl[j] = Wlast[col];
        }
#pragma unroll
        for (int i = 0; i < 4; ++i)
#pragma unroll
            for (int r = 0; r < 4; ++r) {
                int row = bm + wm * 64 + i * 16 + g * 4 + r;
                int cls = tcls[row];
                int jsel = cls & 3;
                bool owner = ((cls >> 2) == wn);
                float cv = 0.f, pnv = 0.f, wlv = 0.f;
#pragma unroll
                for (int j = 0; j < 4; ++j) {
                    bool sel = (j == jsel);
                    cv  = sel ? acc[i][j][r] : cv;
                    pnv = sel ? pn[j] : pnv;
                    wlv = sel ? wl[j] : wlv;
                }
                float dd  = fmaxf(Mnorm[row] + pnv - 2.f * cv, 0.f);
                float d   = sqrtf(dd);
                float sim = __logf((d + 1.0f) / (d + EPS_SIM));
                float kl  = Srow[row] + dd * (0.5f / 256.f);
                float klw = kl * sim;
                float num = klw;
                float den = (klw > 0.0f) ? sim : 0.0f;
                float ov  = sim * wlv;
                num += __shfl_xor(num, 1, 64); den += __shfl_xor(den, 1, 64); ov += __shfl_xor(ov, 1, 64);
                num += __shfl_xor(num, 2, 64); den += __shfl_xor(den, 2, 64); ov += __shfl_xor(ov, 2, 64);
                num += __shfl_xor(num, 4, 64); den += __shfl_xor(den, 4, 64); ov += __shfl_xor(ov, 4, 64);
                num += __shfl_xor(num, 8, 64); den += __shfl_xor(den, 8, 64); ov += __shfl_xor(ov, 8, 64);
                if (owner && rA == 0) {
                    out[row] = ov;
                    atomicAdd(&klacc, num / den);   // LDS atomic
                }
            }
        __syncthreads();
        if (t == 0) {
            atomicAdd(kl_out, klacc * (1.f / (float)B_ROWS));
            if (blockIdx.x == 0) {       // ortho finalize: one thread, plain store
                float o = 0.f;
#pragma unroll
                for (int c = 0; c < 8; ++c) o += opart[c];
                out[OR_IDX] = o * (1.f / 8.f);
            }
        }
        return;
    }

    float bv[4];
#pragma unroll
    for (int j = 0; j < 4; ++j) bv[j] = bias[bn + wn * 64 + j * 16 + rA];

    if (MODE == 4 && y >= 2) {
        // logVar columns: S[row] += partial mean(0.5 e^lv - 0.5 lv - 0.5)
#pragma unroll
        for (int i = 0; i < 4; ++i)
#pragma unroll
            for (int r = 0; r < 4; ++r) {
                int row = bm + wm * 64 + i * 16 + g * 4 + r;
                float s = 0.f;
#pragma unroll
                for (int j = 0; j < 4; ++j) {
                    float lv = acc[i][j][r] + bv[j];
                    lv = fminf(fmaxf(lv, LOG_MIN_F), -LOG_MIN_F);
                    s += 0.5f * __expf(lv) - 0.5f * lv - 0.5f;
                }
                s += __shfl_xor(s, 1, 64); s += __shfl_xor(s, 2, 64);
                s += __shfl_xor(s, 4, 64); s += __shfl_xor(s, 8, 64);
                if (rA == 0) atomicAdd(&Srow[row], s * (1.f / 256.f));
            }
        return;
    }

#pragma unroll
    for (int i = 0; i < 4; ++i)
#pragma unroll
        for (int r = 0; r < 4; ++r) {
            size_t row = bm + wm * 64 + i * 16 + g * 4 + r;
            float sq = 0.f;
#pragma unroll
            for (int j = 0; j < 4; ++j) {
                int col = bn + wn * 64 + j * 16 + rA;
                float v = acc[i][j][r] + bv[j];
                if (MODE == 0 || MODE == 5) v = fmaxf(v, 0.f);
                if (MODE == 3) {
                    float e = __expf(2.f * v);
                    Cf[row * ldc + col] = 1.f - 2.f / (e + 1.f);
                } else {
                    f16 hv = (f16)v;
                    C16[row * ldc + col] = hv;
                    if (MODE == 4) {       // |mu_h|^2 from the ROUNDED value
                        float vr = (float)hv;
                        sq = fmaf(vr, vr, sq);
                    }
                }
            }
            if (MODE == 4) {   // |mu|^2 partial for this wave's 64 cols
                sq += __shfl_xor(sq, 1, 64); sq += __shfl_xor(sq, 2, 64);
                sq += __shfl_xor(sq, 4, 64); sq += __shfl_xor(sq, 8, 64);
                if (rA == 0) atomicAdd(&Mnorm[row], sq);
            }
        }
}

// ---------------------------------------------------------------------------
extern "C" void kernel_launch(void* const* d_in, const int* in_sizes, int n_in,
                              void* d_out, int out_size, void* d_ws, size_t ws_size,
                              hipStream_t stream)
{
    const float* x      = (const float*)d_in[0];
    const int*   tcls   = (const int*)  d_in[1];
    const float* protos = (const float*)d_in[2];
    const float* W1     = (const float*)d_in[3];
    const float* b1     = (const float*)d_in[4];
    const float* W2     = (const float*)d_in[5];
    const float* b2     = (const float*)d_in[6];
    const float* Wd1    = (const float*)d_in[7];
    const float* bd1    = (const float*)d_in[8];
    const float* Wd2    = (const float*)d_in[9];
    const float* bd2    = (const float*)d_in[10];
    const float* Wlast  = (const float*)d_in[11];

    float* out     = (float*)d_out;
    float* decoded = out + B_ROWS;

    // h (f16, 16MB) lives in d_out's decoded region (33.5MB), overwritten by G4
    f16* h_h = (f16*)decoded;

    // workspace: x_h 16MB | mu_h 8MB | dh_h 8MB | S ... | weights ...
    f16* wsf  = (f16*)d_ws;
    f16* x_h  = wsf;                         // 8388608 f16
    f16* mu_h = wsf + 8388608;               // 4194304 f16
    f16* dh_h = wsf + 12582912;              // 4194304 f16

    float* S = (float*)((char*)d_ws + 33554432);
    f16* w = (f16*)(S + 32768);
    f16 *W1h = w, *W2h = w + 262144, *Wd1h = w + 524288, *Wd2h = w + 589824;
    f16 *ph  = w + 720896;                   // protos f16 (128x256)
    float* munorm = (float*)(w + 753664);    // 16384 f32
    float* pnorm  = munorm + 16384;          // 128 f32
    float* opart  = pnorm + 128;             // 8 f32

    // prep: ortho partials + conversions + pnorm + init
    hipLaunchKernelGGL(prep_kernel, dim3(9002), dim3(256), 0, stream,
                       x, W1, W2, Wd1, Wd2, protos,
                       x_h, W1h, W2h, Wd1h, Wd2h, ph,
                       pnorm, opart, S, munorm, out);

    // G1: h = relu(x @ W1^T + b1) -> f16
    hipLaunchKernelGGL((gemm_mfma<0, 512>), dim3(128, 4), dim3(256), 0, stream,
                       x_h, W1h, (f16*)nullptr, b1,
                       h_h, (float*)nullptr, (float*)nullptr, (float*)nullptr,
                       (int*)nullptr, (float*)nullptr, (float*)nullptr, (float*)nullptr,
                       (float*)nullptr, (float*)nullptr, 512);
    // G2: conv = h @ W2^T + b2 -> mu f16 + |mu|^2 (y<2); S row-sums (y>=2)
    hipLaunchKernelGGL((gemm_mfma<4, 512>), dim3(128, 4), dim3(256), 0, stream,
                       h_h, W2h, (f16*)nullptr, b2,
                       mu_h, (float*)nullptr, S, munorm,
                       (int*)nullptr, (float*)nullptr, (float*)nullptr, (float*)nullptr,
                       (float*)nullptr, (float*)nullptr, 256);
    // G3': y<2: dh = relu(mu @ Wd1^T + bd1); y==2: proto dist + sim/kl/out + ortho fin
    hipLaunchKernelGGL((gemm_mfma<5, 256>), dim3(128, 3), dim3(256), 0, stream,
                       mu_h, Wd1h, ph, bd1,
                       dh_h, (float*)nullptr, S, munorm,
                       tcls, pnorm, Wlast, opart,
                       out, out + KL_IDX, 256);
    // G4: decoded = tanh(dh @ Wd2^T + bd2) -> f32 (overwrites h region)
    hipLaunchKernelGGL((gemm_mfma<3, 256>), dim3(128, 4), dim3(256), 0, stream,
                       dh_h, Wd2h, (f16*)nullptr, bd2,
                       (f16*)nullptr, decoded, (float*)nullptr, (float*)nullptr,
                       (int*)nullptr, (float*)nullptr, (float*)nullptr, (float*)nullptr,
                       (float*)nullptr, (float*)nullptr, 512);
}

// Round 14
// 77.049 us; speedup vs baseline: 1.8835x; 1.0553x over previous
//
#include <hip/hip_runtime.h>
#include <math.h>

typedef unsigned short u16;
typedef unsigned int   u32;
typedef _Float16 f16;
typedef f16   f16x4 __attribute__((ext_vector_type(4)));
typedef f16   f16x8 __attribute__((ext_vector_type(8)));
typedef float f32x4 __attribute__((ext_vector_type(4)));

#define B_ROWS 16384
#define PC 16
#define EPS_SIM 1e-4f
#define LOG_MIN_F (-18.420680743952367f)
#define KL_IDX  (B_ROWS + B_ROWS * 512)   // 8404992
#define OR_IDX  (KL_IDX + 1)

// direct global->LDS async copy, 16B per lane (lds dest = uniform base + lane*16)
#define GLD16(gp, lp) __builtin_amdgcn_global_load_lds( \
    (const __attribute__((address_space(1))) void*)(gp), \
    (__attribute__((address_space(3))) void*)(lp), 16, 0, 0)

// ---------------------------------------------------------------------------
// prep: ortho partials (blocks 0-7) + f32->f16 conversions + pnorm + init
// ---------------------------------------------------------------------------
__device__ __forceinline__ void conv4(const float* __restrict__ src,
                                      f16* __restrict__ dst, int i)
{
    float4 v = ((const float4*)src)[i];
    f16x4 o = { (f16)v.x, (f16)v.y, (f16)v.z, (f16)v.w };
    ((f16x4*)dst)[i] = o;
}

__global__ __launch_bounds__(256)
void prep_kernel(const float* __restrict__ x,   const float* __restrict__ W1,
                 const float* __restrict__ W2,  const float* __restrict__ Wd1,
                 const float* __restrict__ Wd2, const float* __restrict__ protos,
                 f16* __restrict__ x_h,  f16* __restrict__ W1h,
                 f16* __restrict__ W2h,  f16* __restrict__ Wd1h,
                 f16* __restrict__ Wd2h, f16* __restrict__ ph,
                 float* __restrict__ pnorm, float* __restrict__ opart,
                 float* __restrict__ S, float* __restrict__ Mn,
                 float* __restrict__ out)
{
    __shared__ float pk[PC][257];
    __shared__ float red[256];
    int blk = blockIdx.x, t = threadIdx.x;

    if (blk < 8) {                      // ortho: one class per block, parallel
        int c = blk;
        for (int i = t; i < PC * 256; i += 256)
            pk[i >> 8][i & 255] = protos[c * PC * 256 + i];
        __syncthreads();
        float mean = 0.f;
#pragma unroll
        for (int i = 0; i < PC; ++i) mean += pk[i][t];
        mean *= (1.f / (float)PC);
#pragma unroll
        for (int i = 0; i < PC; ++i) pk[i][t] -= mean;
        __syncthreads();
        int i = t >> 4, j = t & 15;
        float gg = 0.f;
#pragma unroll 8
        for (int l = 0; l < 256; ++l) gg = fmaf(pk[i][l], pk[j][l], gg);
        gg -= (i == j) ? 1.f : 0.f;
        red[t] = gg * gg;
        __syncthreads();
        for (int s = 128; s; s >>= 1) { if (t < s) red[t] += red[t + s]; __syncthreads(); }
        if (t == 0) opart[c] = sqrtf(red[0]);     // plain store, summed later
        return;
    }
    int b2 = blk - 8;
    if (b2 < 8192)         conv4(x,   x_h,  b2 * 256 + t);
    else if (b2 < 8448)    conv4(W1,  W1h,  (b2 - 8192) * 256 + t);
    else if (b2 < 8704)    conv4(W2,  W2h,  (b2 - 8448) * 256 + t);
    else if (b2 < 8768)    conv4(Wd1, Wd1h, (b2 - 8704) * 256 + t);
    else if (b2 < 8896)    conv4(Wd2, Wd2h, (b2 - 8768) * 256 + t);
    else if (b2 < 8928)    conv4(protos, ph, (b2 - 8896) * 256 + t);
    else if (b2 < 8930) {
        // pnorm from f16-ROUNDED protos (consistent with MFMA cross term)
        int tt = (b2 - 8928) * 256 + t;            // [0,512)
        int row = tt >> 2, q = tt & 3;
        const float* pr = protos + (size_t)row * 256 + q * 64;
        float s = 0.f;
#pragma unroll
        for (int j = 0; j < 16; ++j) {
            float4 v = *(const float4*)(pr + j * 4);
            float r0 = (float)(f16)v.x, r1 = (float)(f16)v.y;
            float r2 = (float)(f16)v.z, r3 = (float)(f16)v.w;
            s = fmaf(r0, r0, s); s = fmaf(r1, r1, s);
            s = fmaf(r2, r2, s); s = fmaf(r3, r3, s);
        }
        s += __shfl_xor(s, 1, 64);
        s += __shfl_xor(s, 2, 64);
        if (q == 0) pnorm[row] = s;
    } else {
        int i = (b2 - 8930) * 256 + t;             // [0,16384)
        S[i] = 0.f; Mn[i] = 0.f;
        if (i == 0) out[KL_IDX] = 0.f;
    }
}

// ---------------------------------------------------------------------------
// Pure-f16 MFMA GEMM, BM=128 x BN=128, BK=32, 4 waves (2x2, 64x64 each),
// 16KB LDS, two-barrier loop.
// MODE 0: relu -> f16 store
// MODE 3: tanh -> f32 store
// MODE 4: y<2 mu f16 store + |mu_h|^2 row-reduce; y>=2 logVar -> S row-reduce
// MODE 5: y<2 relu f16 store (dh); y==2 raw f16 store of cross to Xc
//         (NO per-row reductions here — proto_finish does them in-lane)
// ---------------------------------------------------------------------------
template<int MODE, int KK>
__global__ __launch_bounds__(256, 2)
void gemm_mfma(const f16* __restrict__ A, const f16* __restrict__ B,
               const f16* __restrict__ P, const float* __restrict__ bias,
               f16* __restrict__ C16, float* __restrict__ Cf,
               float* __restrict__ Srow, float* __restrict__ Mnorm,
               f16* __restrict__ Xc, int ldc)
{
    __shared__ __align__(16) f16 LA[128][32];
    __shared__ __align__(16) f16 LB[128][32];

    const int t = threadIdx.x, lane = t & 63, wave = t >> 6;
    const int wm = wave >> 1, wn = wave & 1;
    const int bm = blockIdx.x * 128;
    const int y  = blockIdx.y;
    const bool proto = (MODE == 5) && (y == 2);
    const int bn  = y * 128;                      // output col base (non-proto)
    const int bnB = proto ? 0 : bn;               // B row base
    const f16* Bp = proto ? P : B;
    const int rA = lane & 15, g = lane >> 4;
    const int srow = lane >> 2, cp = lane & 3;    // staging: 16 rows x 4 chunks

    f32x4 acc[4][4];
    const f32x4 z4 = {0.f, 0.f, 0.f, 0.f};
#pragma unroll
    for (int i = 0; i < 4; ++i)
#pragma unroll
        for (int j = 0; j < 4; ++j) acc[i][j] = z4;

    auto stage = [&](int kt) {   // 4 GLD16 per thread (2 A-slabs + 2 B-slabs)
#pragma unroll
        for (int s = 0; s < 2; ++s) {
            int row = wave * 32 + s * 16 + srow;
            int lc  = (cp - (row >> 1)) & 3;      // inverse swizzle on SOURCE
            GLD16(A  + (size_t)(bm  + row) * KK + kt * 32 + lc * 8,
                  &LA[wave * 32 + s * 16][0]);
            GLD16(Bp + (size_t)(bnB + row) * KK + kt * 32 + lc * 8,
                  &LB[wave * 32 + s * 16][0]);
        }
    };

    constexpr int T = KK / 32;
    stage(0);
    for (int tk = 0; tk < T; ++tk) {
        __syncthreads();                 // vmcnt drained: tile tk in LDS

        f16x8 a[4], b[4];
#pragma unroll
        for (int i = 0; i < 4; ++i) {
            int m = wm * 64 + i * 16 + rA;
            int c = ((g + (m >> 1)) & 3) * 8;     // swizzled READ
            a[i] = *(const f16x8*)&LA[m][c];
            int n = wn * 64 + i * 16 + rA;
            int cn = ((g + (n >> 1)) & 3) * 8;
            b[i] = *(const f16x8*)&LB[n][cn];
        }

        __syncthreads();                 // all reads done; safe to overwrite
        if (tk + 1 < T) stage(tk + 1);   // loads fly under the 16 MFMAs

#pragma unroll
        for (int i = 0; i < 4; ++i)
#pragma unroll
            for (int j = 0; j < 4; ++j)
                acc[i][j] = __builtin_amdgcn_mfma_f32_16x16x32_f16(a[i], b[j], acc[i][j], 0, 0, 0);
    }

    if (proto) {
        // raw cross-products -> Xc[16384][128] as f16 (no bias, no reduce)
#pragma unroll
        for (int i = 0; i < 4; ++i)
#pragma unroll
            for (int r = 0; r < 4; ++r) {
                size_t row = bm + wm * 64 + i * 16 + g * 4 + r;
#pragma unroll
                for (int j = 0; j < 4; ++j) {
                    int col = wn * 64 + j * 16 + rA;
                    Xc[row * 128 + col] = (f16)acc[i][j][r];
                }
            }
        return;
    }

    float bv[4];
#pragma unroll
    for (int j = 0; j < 4; ++j) bv[j] = bias[bn + wn * 64 + j * 16 + rA];

    if (MODE == 4 && y >= 2) {
        // logVar columns: S[row] += partial mean(0.5 e^lv - 0.5 lv - 0.5)
#pragma unroll
        for (int i = 0; i < 4; ++i)
#pragma unroll
            for (int r = 0; r < 4; ++r) {
                int row = bm + wm * 64 + i * 16 + g * 4 + r;
                float s = 0.f;
#pragma unroll
                for (int j = 0; j < 4; ++j) {
                    float lv = acc[i][j][r] + bv[j];
                    lv = fminf(fmaxf(lv, LOG_MIN_F), -LOG_MIN_F);
                    s += 0.5f * __expf(lv) - 0.5f * lv - 0.5f;
                }
                s += __shfl_xor(s, 1, 64); s += __shfl_xor(s, 2, 64);
                s += __shfl_xor(s, 4, 64); s += __shfl_xor(s, 8, 64);
                if (rA == 0) atomicAdd(&Srow[row], s * (1.f / 256.f));
            }
        return;
    }

#pragma unroll
    for (int i = 0; i < 4; ++i)
#pragma unroll
        for (int r = 0; r < 4; ++r) {
            size_t row = bm + wm * 64 + i * 16 + g * 4 + r;
            float sq = 0.f;
#pragma unroll
            for (int j = 0; j < 4; ++j) {
                int col = bn + wn * 64 + j * 16 + rA;
                float v = acc[i][j][r] + bv[j];
                if (MODE == 0 || MODE == 5) v = fmaxf(v, 0.f);
                if (MODE == 3) {
                    float e = __expf(2.f * v);
                    Cf[row * ldc + col] = 1.f - 2.f / (e + 1.f);
                } else {
                    f16 hv = (f16)v;
                    C16[row * ldc + col] = hv;
                    if (MODE == 4) {       // |mu_h|^2 from the ROUNDED value
                        float vr = (float)hv;
                        sq = fmaf(vr, vr, sq);
                    }
                }
            }
            if (MODE == 4) {   // |mu|^2 partial for this wave's 64 cols
                sq += __shfl_xor(sq, 1, 64); sq += __shfl_xor(sq, 2, 64);
                sq += __shfl_xor(sq, 4, 64); sq += __shfl_xor(sq, 8, 64);
                if (rA == 0) atomicAdd(&Mnorm[row], sq);
            }
        }
}

// ---------------------------------------------------------------------------
// proto_finish: one ROW PER LANE, zero shuffles in the proto loop.
// d^2 = |mu|^2 + |p|^2 - 2*cross; sim/kl/out in-lane; one 6-shfl wave
// reduce per WAVE for the kl mean; ortho finalize in block 0.
// ---------------------------------------------------------------------------
__global__ __launch_bounds__(256)
void proto_finish(const f16* __restrict__ Xc, const float* __restrict__ Mnorm,
                  const float* __restrict__ Sr, const int* __restrict__ tcls,
                  const float* __restrict__ pnorm, const float* __restrict__ Wlast,
                  const float* __restrict__ opart,
                  float* __restrict__ out, float* __restrict__ kl_out)
{
    __shared__ float pnS[128], wlS[128], red[4];
    int t = threadIdx.x;
    if (t < 128) { pnS[t] = pnorm[t]; wlS[t] = Wlast[t]; }
    __syncthreads();

    int b = blockIdx.x * 256 + t;
    int cls = tcls[b];
    float Mn = Mnorm[b], Sb = Sr[b];
    const f16* xr = Xc + (size_t)b * 128 + cls * 16;
    f16x8 c0 = *(const f16x8*)xr;
    f16x8 c1 = *(const f16x8*)(xr + 8);

    float num = 0.f, den = 0.f, ov = 0.f;
#pragma unroll
    for (int p = 0; p < 16; ++p) {
        float c  = (p < 8) ? (float)c0[p] : (float)c1[p - 8];
        int  ip  = cls * 16 + p;
        float dd = fmaxf(Mn + pnS[ip] - 2.f * c, 0.f);
        float d  = sqrtf(dd);
        float sim = __logf((d + 1.f) / (d + EPS_SIM));
        float kl  = Sb + dd * (0.5f / 256.f);
        float klw = kl * sim;
        num += klw;
        den += (klw > 0.f) ? sim : 0.f;
        ov  += sim * wlS[ip];
    }
    out[b] = ov;

    float v = num / den;
#pragma unroll
    for (int off = 32; off; off >>= 1) v += __shfl_xor(v, off, 64);
    int lane = t & 63, w = t >> 6;
    if (lane == 0) red[w] = v;
    __syncthreads();
    if (t == 0)
        atomicAdd(kl_out, (red[0] + red[1] + red[2] + red[3]) * (1.f / (float)B_ROWS));
    if (blockIdx.x == 0 && t == 0) {
        float o = 0.f;
#pragma unroll
        for (int c8 = 0; c8 < 8; ++c8) o += opart[c8];
        out[OR_IDX] = o * (1.f / 8.f);
    }
}

// ---------------------------------------------------------------------------
extern "C" void kernel_launch(void* const* d_in, const int* in_sizes, int n_in,
                              void* d_out, int out_size, void* d_ws, size_t ws_size,
                              hipStream_t stream)
{
    const float* x      = (const float*)d_in[0];
    const int*   tcls   = (const int*)  d_in[1];
    const float* protos = (const float*)d_in[2];
    const float* W1     = (const float*)d_in[3];
    const float* b1     = (const float*)d_in[4];
    const float* W2     = (const float*)d_in[5];
    const float* b2     = (const float*)d_in[6];
    const float* Wd1    = (const float*)d_in[7];
    const float* bd1    = (const float*)d_in[8];
    const float* Wd2    = (const float*)d_in[9];
    const float* bd2    = (const float*)d_in[10];
    const float* Wlast  = (const float*)d_in[11];

    float* out     = (float*)d_out;
    float* decoded = out + B_ROWS;

    // h (f16, 16MB) lives in d_out's decoded region (33.5MB), overwritten by G4
    f16* h_h = (f16*)decoded;

    // workspace: x_h 16MB | mu_h 8MB | dh_h 8MB | S ... | weights ... | Xc 4MB
    f16* wsf  = (f16*)d_ws;
    f16* x_h  = wsf;                         // 8388608 f16
    f16* mu_h = wsf + 8388608;               // 4194304 f16
    f16* dh_h = wsf + 12582912;              // 4194304 f16

    float* S = (float*)((char*)d_ws + 33554432);
    f16* w = (f16*)(S + 32768);
    f16 *W1h = w, *W2h = w + 262144, *Wd1h = w + 524288, *Wd2h = w + 589824;
    f16 *ph  = w + 720896;                   // protos f16 (128x256)
    float* munorm = (float*)(w + 753664);    // 16384 f32
    float* pnorm  = munorm + 16384;          // 128 f32
    float* opart  = pnorm + 128;             // 8 f32
    f16* Xc = (f16*)((char*)d_ws + 37748736);// 36MB offset: 16384x128 f16 (4MB)

    // prep: ortho partials + conversions + pnorm + init
    hipLaunchKernelGGL(prep_kernel, dim3(9002), dim3(256), 0, stream,
                       x, W1, W2, Wd1, Wd2, protos,
                       x_h, W1h, W2h, Wd1h, Wd2h, ph,
                       pnorm, opart, S, munorm, out);

    // G1: h = relu(x @ W1^T + b1) -> f16
    hipLaunchKernelGGL((gemm_mfma<0, 512>), dim3(128, 4), dim3(256), 0, stream,
                       x_h, W1h, (f16*)nullptr, b1,
                       h_h, (float*)nullptr, (float*)nullptr, (float*)nullptr,
                       (f16*)nullptr, 512);
    // G2: conv = h @ W2^T + b2 -> mu f16 + |mu|^2 (y<2); S row-sums (y>=2)
    hipLaunchKernelGGL((gemm_mfma<4, 512>), dim3(128, 4), dim3(256), 0, stream,
                       h_h, W2h, (f16*)nullptr, b2,
                       mu_h, (float*)nullptr, S, munorm,
                       (f16*)nullptr, 256);
    // G3': y<2: dh = relu(mu @ Wd1^T + bd1); y==2: cross -> Xc (raw f16)
    hipLaunchKernelGGL((gemm_mfma<5, 256>), dim3(128, 3), dim3(256), 0, stream,
                       mu_h, Wd1h, ph, bd1,
                       dh_h, (float*)nullptr, (float*)nullptr, (float*)nullptr,
                       Xc, 256);
    // proto_finish: in-lane per-row d^2/sim/kl + out + kl mean + ortho fin
    hipLaunchKernelGGL(proto_finish, dim3(64), dim3(256), 0, stream,
                       Xc, munorm, S, tcls, pnorm, Wlast, opart,
                       out, out + KL_IDX);
    // G4: decoded = tanh(dh @ Wd2^T + bd2) -> f32 (overwrites h region)
    hipLaunchKernelGGL((gemm_mfma<3, 256>), dim3(128, 4), dim3(256), 0, stream,
                       dh_h, Wd2h, (f16*)nullptr, bd2,
                       (f16*)nullptr, decoded, (float*)nullptr, (float*)nullptr,
                       (f16*)nullptr, 512);
}